// Round 4
// baseline (275.621 us; speedup 1.0000x reference)
//
#include <hip/hip_runtime.h>

#define NE 500000
#define NB 256
#define D  128
#define NT 7813           // ceil(NE/64)
#define GMAIN 1024        // grid for k_main (1 block/CU, 4 rounds)
#define SPLIT 16          // chunks per graph in k_accum2
#define APAD 8            // stride (u32) so each atomic counter sits on its own 32B
#define SCHUNK 1954       // ceil(NE/256)

typedef __attribute__((ext_vector_type(8))) short bf16x8;
typedef __attribute__((ext_vector_type(4))) float f32x4;

__device__ __forceinline__ float lrelu(float x){ return x > 0.0f ? x : 0.01f * x; }

// f32 -> bf16 (round-to-nearest-even), header-free
__device__ __forceinline__ unsigned short f2bf(float f){
  unsigned u = __float_as_uint(f);
  unsigned rounding = 0x7fffu + ((u >> 16) & 1u);
  return (unsigned short)((u + rounding) >> 16);
}

// monotonic float<->uint encoding for atomicMax on signed floats
__device__ __forceinline__ unsigned encf(float f){
  unsigned u = __float_as_uint(f);
  return (u & 0x80000000u) ? ~u : (u | 0x80000000u);
}
__device__ __forceinline__ float decf(unsigned u){
  return (u & 0x80000000u) ? __uint_as_float(u & 0x7fffffffu) : __uint_as_float(~u);
}

__global__ void k_init(unsigned* gmax, float* gsum, unsigned* hist){
  int t = threadIdx.x;
  if (t < NB){ gmax[t*APAD] = 0u; gsum[t*APAD] = 0.0f; hist[t*APAD] = 0u; }
}

// k = lrelu(u@Wk + bk); qu = u@Wq[128:] + bq; vu = u@Wv[128:] + bv
__global__ void k_pre(const float* __restrict__ u,  const float* __restrict__ Wq,
                      const float* __restrict__ bq, const float* __restrict__ Wk,
                      const float* __restrict__ bk, const float* __restrict__ Wv,
                      const float* __restrict__ bv,
                      float* __restrict__ kT, float* __restrict__ qu, float* __restrict__ vu){
  __shared__ float us[D];
  int b = blockIdx.x, c = threadIdx.x;
  us[c] = u[b*D + c];
  __syncthreads();
  float ka = bk[c], qa = bq[c], va = bv[c];
  #pragma unroll 4
  for (int j = 0; j < D; ++j){
    float uv = us[j];
    ka += uv * Wk[j*D + c];
    qa += uv * Wq[(D + j)*D + c];
    va += uv * Wv[(D + j)*D + c];
  }
  kT[b*D + c] = lrelu(ka);
  qu[b*D + c] = qa;
  vu[b*D + c] = va;
}

// WqT/WvT[c][k] = bf16(W[k][c]) for k<128 (edge half of the weight)
__global__ void k_prew(const float* __restrict__ Wq, const float* __restrict__ Wv,
                       unsigned short* __restrict__ WqT, unsigned short* __restrict__ WvT){
  int c = blockIdx.x, k = threadIdx.x;
  WqT[c*D + k] = f2bf(Wq[k*D + c]);
  WvT[c*D + k] = f2bf(Wv[k*D + c]);
}

// ---- MFMA helpers (LDS layout: row-major, 256B rows, 16B-chunk XOR swizzle) ----
__device__ __forceinline__ void stage_weights(unsigned short* wt, const unsigned short* Wsrc, int tid){
  const uint4* wsrc = (const uint4*)Wsrc;      // 128x128 bf16 = 2048 uint4
  for (int i = tid; i < 2048; i += 256){
    int c = i >> 4, off = (i & 15) << 4;
    *(uint4*)((char*)wt + c*256 + (off ^ ((c & 7) << 4))) = wsrc[i];
  }
}

__device__ __forceinline__ void load_rows(float4 pf[8], const float* __restrict__ edges,
                                          int t, int r, int q){
  long e = (long)t * 64 + r; if (e >= NE) e = NE - 1;
  const float4* src = (const float4*)(edges + (size_t)e * D + q * 32);
  #pragma unroll
  for (int i = 0; i < 8; ++i) pf[i] = src[i];
}

__device__ __forceinline__ void conv_rows(unsigned short* xs, const float4 pf[8], int r, int q){
  char* xrow = (char*)xs + r * 256;
  #pragma unroll
  for (int ci = 0; ci < 4; ++ci){
    float4 a = pf[2*ci], b = pf[2*ci + 1];
    bf16x8 pk;
    pk[0] = (short)f2bf(a.x); pk[1] = (short)f2bf(a.y);
    pk[2] = (short)f2bf(a.z); pk[3] = (short)f2bf(a.w);
    pk[4] = (short)f2bf(b.x); pk[5] = (short)f2bf(b.y);
    pk[6] = (short)f2bf(b.z); pk[7] = (short)f2bf(b.w);
    int off = q * 64 + ci * 16;
    *(bf16x8*)(xrow + (off ^ ((r & 7) << 4))) = pk;
  }
}

// Fused single pass over edges:
//   scores[e] = lrelu(edges[e]@Wq[:128] + qu[eb]) . k[eb] / sqrt(128)  (+ per-graph max/count)
//   vprime[e][m*8+n] = bf16(lrelu(edges[e]@Wv[:128] + vu[eb]))[col=16n+m]
__global__ __launch_bounds__(256)
void k_main(const float* __restrict__ edges, const int* __restrict__ send,
            const int* __restrict__ batch, const unsigned short* __restrict__ WqT,
            const unsigned short* __restrict__ WvT, const float* __restrict__ qu,
            const float* __restrict__ vu, const float* __restrict__ kT,
            float* __restrict__ scores, int* __restrict__ ebArr,
            unsigned short* __restrict__ vprime, unsigned* gmax, unsigned* hist){
  __shared__ __align__(16) unsigned short wq[D * D];     // 32 KB
  __shared__ __align__(16) unsigned short wv[D * D];     // 32 KB
  __shared__ __align__(16) unsigned short xs[2][64 * D]; // 2 x 16 KB
  __shared__ int ebs[2][64];
  __shared__ unsigned lmax[NB], lcnt[NB];

  const int tid = threadIdx.x;
  stage_weights(wq, WqT, tid);
  stage_weights(wv, WvT, tid);
  lmax[tid] = 0u; lcnt[tid] = 0u;

  const int lane = tid & 63, w = tid >> 6, g = lane >> 4, m = lane & 15;
  const int r = tid >> 2, q = tid & 3;

  float4 pf[8];
  int svp = 0;
  const int t0 = blockIdx.x;
  load_rows(pf, edges, t0, r, q);
  if (tid < 64){ long e = (long)t0 * 64 + tid; if (e >= NE) e = NE - 1; svp = send[e]; }
  int cur = 0;

  for (int t = t0; t < NT; t += GMAIN, cur ^= 1){
    // convert phase: prefetched regs -> LDS (waits the outstanding loads)
    conv_rows(xs[cur], pf, r, q);
    if (tid < 64){
      int eb = batch[svp];
      ebs[cur][tid] = eb;
      long e = (long)t * 64 + tid;
      if (e < NE) ebArr[e] = eb;
    }
    // issue next tile's loads early (overlap with compute below)
    int tn = t + GMAIN;
    if (tn < NT){
      load_rows(pf, edges, tn, r, q);
      if (tid < 64){ long e = (long)tn * 64 + tid; if (e >= NE) e = NE - 1; svp = send[e]; }
    }
    __syncthreads();

    int ebj[4];
    #pragma unroll
    for (int j = 0; j < 4; ++j) ebj[j] = ebs[cur][16*w + 4*g + j];
    f32x4 qa[8], va[8];
    #pragma unroll
    for (int n = 0; n < 8; ++n){
      #pragma unroll
      for (int j = 0; j < 4; ++j){
        qa[n][j] = qu[(size_t)ebj[j] * D + 16*n + m];   // bias as MFMA C-in
        va[n][j] = vu[(size_t)ebj[j] * D + 16*n + m];
      }
    }
    const int arow = 16*w + m;
    #pragma unroll
    for (int ks = 0; ks < 4; ++ks){
      int koff = ks * 64 + (g << 4);
      bf16x8 af = *(const bf16x8*)((const char*)xs[cur] + arow*256 + (koff ^ ((arow & 7) << 4)));
      #pragma unroll
      for (int n = 0; n < 8; ++n){
        int bc = 16*n + m;
        int boff = koff ^ ((bc & 7) << 4);
        bf16x8 bqf = *(const bf16x8*)((const char*)wq + bc*256 + boff);
        qa[n] = __builtin_amdgcn_mfma_f32_16x16x32_bf16(af, bqf, qa[n], 0, 0, 0);
        bf16x8 bvf = *(const bf16x8*)((const char*)wv + bc*256 + boff);
        va[n] = __builtin_amdgcn_mfma_f32_16x16x32_bf16(af, bvf, va[n], 0, 0, 0);
      }
    }
    // epilogues
    #pragma unroll
    for (int j = 0; j < 4; ++j){
      int er = 16*w + 4*g + j;
      long e = (long)t * 64 + er;
      bf16x8 pk;
      #pragma unroll
      for (int n = 0; n < 8; ++n) pk[n] = (short)f2bf(lrelu(va[n][j]));
      if (e < NE) *(bf16x8*)(vprime + (size_t)e * D + m*8) = pk;

      float p = 0.0f;
      const float* krow = kT + (size_t)ebj[j] * D;
      #pragma unroll
      for (int n = 0; n < 8; ++n) p += lrelu(qa[n][j]) * krow[16*n + m];
      p += __shfl_xor(p, 1); p += __shfl_xor(p, 2);
      p += __shfl_xor(p, 4); p += __shfl_xor(p, 8);
      if (m == 0 && e < NE){
        float sc = p * 0.08838834764831843f; // 1/sqrt(128)
        scores[e] = sc;
        atomicMax(&lmax[ebj[j]], encf(sc));
        atomicAdd(&lcnt[ebj[j]], 1u);
      }
    }
    __syncthreads();
  }
  // merge per-block stats (tid indexes the 256 graphs exactly)
  unsigned c = lcnt[tid];
  if (c){ atomicAdd(&hist[tid*APAD], c); atomicMax(&gmax[tid*APAD], lmax[tid]); }
}

__global__ void k_scan(const unsigned* __restrict__ hist, unsigned* __restrict__ offs,
                       unsigned* cursor){
  __shared__ unsigned sh[NB];
  __shared__ unsigned so[NB + 1];
  int tid = threadIdx.x;
  sh[tid] = hist[tid*APAD];
  __syncthreads();
  if (tid == 0){
    unsigned run = 0;
    for (int b = 0; b < NB; ++b){ so[b] = run; run += sh[b]; }
    so[NB] = run;
  }
  __syncthreads();
  offs[tid] = so[tid];
  cursor[tid*APAD] = so[tid];
  if (tid == 0) offs[NB] = so[NB];
}

// counting-sort scatter (block-batched) + per-graph sum of exp(score - max)
__global__ __launch_bounds__(256)
void k_scatter(const float* __restrict__ scores, const int* __restrict__ ebArr,
               const unsigned* __restrict__ gmax, unsigned* cursor,
               unsigned* __restrict__ perm, float* gsum){
  __shared__ unsigned lbase[NB];
  __shared__ unsigned lcnt[NB];
  __shared__ float lsum[NB];
  __shared__ float lgm[NB];
  int tid = threadIdx.x;
  lcnt[tid] = 0u; lsum[tid] = 0.0f; lgm[tid] = decf(gmax[tid*APAD]);
  __syncthreads();
  int start = blockIdx.x * SCHUNK;
  int end = start + SCHUNK; if (end > NE) end = NE;
  for (int e = start + tid; e < end; e += 256)
    atomicAdd(&lcnt[ebArr[e]], 1u);
  __syncthreads();
  unsigned c = lcnt[tid];
  lbase[tid] = c ? atomicAdd(&cursor[tid*APAD], c) : 0u;
  lcnt[tid] = 0u;
  __syncthreads();
  for (int e = start + tid; e < end; e += 256){
    int b = ebArr[e];
    unsigned p = lbase[b] + atomicAdd(&lcnt[b], 1u);
    perm[p] = (unsigned)e;
    atomicAdd(&lsum[b], __expf(scores[e] - lgm[b]));
  }
  __syncthreads();
  if (lsum[tid] != 0.0f) atomicAdd(&gsum[tid*APAD], lsum[tid]);
}

// per-(graph,chunk): weighted sum of bf16 v' rows (no GEMM) -> xpart in pos space
__global__ __launch_bounds__(256)
void k_accum2(const unsigned* __restrict__ vp32, const float* __restrict__ scores,
              const unsigned* __restrict__ gmax, const unsigned* __restrict__ offs,
              const unsigned* __restrict__ perm, float* __restrict__ xpart){
  __shared__ float xred[4 * D];
  const int tid = threadIdx.x;
  const int b = blockIdx.x >> 4, chunk = blockIdx.x & (SPLIT - 1);
  const unsigned o0 = offs[b];
  const int count = (int)(offs[b + 1] - o0);
  const int r0 = (int)(((long)count * chunk) / SPLIT);
  const int r1 = (int)(((long)count * (chunk + 1)) / SPLIT);
  const float gm = decf(gmax[b*APAD]);
  const int lane = tid & 63, w = tid >> 6;
  float xa = 0.0f, xb = 0.0f;
  #pragma unroll 4
  for (int i = r0 + w; i < r1; i += 4){
    unsigned e = perm[o0 + i];                       // wave-broadcast load
    float we = __expf(scores[e] - gm);
    unsigned d = vp32[(size_t)e * 64 + lane];        // 256B coalesced row
    xa += we * __uint_as_float(d << 16);
    xb += we * __uint_as_float(d & 0xffff0000u);
  }
  xred[w * D + 2*lane]     = xa;
  xred[w * D + 2*lane + 1] = xb;
  __syncthreads();
  if (tid < D){
    float s = xred[tid] + xred[D + tid] + xred[2*D + tid] + xred[3*D + tid];
    xpart[((size_t)b * SPLIT + chunk) * D + tid] = s;
  }
}

// sum chunks, /gsum, unpermute pos->col, then x@Wl + bl with lrelu
__global__ void k_final(const float* __restrict__ xpart, const float* __restrict__ gsum,
                        const float* __restrict__ Wl, const float* __restrict__ bl,
                        float* __restrict__ out){
  __shared__ float xr[D];     // in pos space
  int b = blockIdx.x, c = threadIdx.x;
  float gs = gsum[b*APAD];
  float s = 0.0f;
  #pragma unroll
  for (int ch = 0; ch < SPLIT; ++ch) s += xpart[((size_t)b * SPLIT + ch) * D + c];
  xr[c] = gs > 0.0f ? s / gs : 0.0f;
  __syncthreads();
  float a = bl[c];
  #pragma unroll 4
  for (int j = 0; j < D; ++j){
    float xv = xr[((j & 15) << 3) + (j >> 4)];   // pos = (col&15)*8 + (col>>4)
    a += xv * Wl[j*D + c];
  }
  out[(size_t)b * D + c] = lrelu(a);
}

extern "C" void kernel_launch(void* const* d_in, const int* in_sizes, int n_in,
                              void* d_out, int out_size, void* d_ws, size_t ws_size,
                              hipStream_t stream){
  // setup_inputs order: nodes, edges, edge_index, u, batch, Wq, bq, Wk, bk, Wv, bv, Wl, bl
  const float* edges = (const float*)d_in[1];
  const int*   send  = (const int*)d_in[2];      // edge_index[0] = first NE ints
  const float* u     = (const float*)d_in[3];
  const int*   batch = (const int*)d_in[4];
  const float* Wq    = (const float*)d_in[5];
  const float* bq    = (const float*)d_in[6];
  const float* Wk    = (const float*)d_in[7];
  const float* bk    = (const float*)d_in[8];
  const float* Wv    = (const float*)d_in[9];
  const float* bv    = (const float*)d_in[10];
  const float* Wl    = (const float*)d_in[11];
  const float* bl    = (const float*)d_in[12];
  float* out = (float*)d_out;

  char* wsb = (char*)d_ws;
  size_t off = 0;
  auto alloc = [&](size_t bytes)->char*{
    char* p = wsb + off; off += (bytes + 255) & ~(size_t)255; return p;
  };
  float*    kT     = (float*)   alloc((size_t)NB * D * 4);
  float*    qu     = (float*)   alloc((size_t)NB * D * 4);
  float*    vu     = (float*)   alloc((size_t)NB * D * 4);
  unsigned* gmax   = (unsigned*)alloc((size_t)NB * APAD * 4);
  float*    gsum   = (float*)   alloc((size_t)NB * APAD * 4);
  unsigned* hist   = (unsigned*)alloc((size_t)NB * APAD * 4);
  unsigned* cursor = (unsigned*)alloc((size_t)NB * APAD * 4);
  unsigned* offs   = (unsigned*)alloc((size_t)(NB + 1) * 4);
  unsigned short* WqTb = (unsigned short*)alloc((size_t)D * D * 2);
  unsigned short* WvTb = (unsigned short*)alloc((size_t)D * D * 2);
  float*    xpart  = (float*)   alloc((size_t)NB * SPLIT * D * 4);
  float*    scores = (float*)   alloc((size_t)NE * 4);
  int*      ebArr  = (int*)     alloc((size_t)NE * 4);
  unsigned* perm   = (unsigned*)alloc((size_t)NE * 4);
  unsigned short* vprime = (unsigned short*)alloc((size_t)NE * D * 2);  // 128 MB
  (void)ws_size; (void)in_sizes; (void)n_in; (void)out_size;

  k_init   <<<1, 256, 0, stream>>>(gmax, gsum, hist);
  k_pre    <<<NB, D, 0, stream>>>(u, Wq, bq, Wk, bk, Wv, bv, kT, qu, vu);
  k_prew   <<<D, D, 0, stream>>>(Wq, Wv, WqTb, WvTb);
  k_main   <<<GMAIN, 256, 0, stream>>>(edges, send, batch, WqTb, WvTb, qu, vu, kT,
                                       scores, ebArr, vprime, gmax, hist);
  k_scan   <<<1, 256, 0, stream>>>(hist, offs, cursor);
  k_scatter<<<256, 256, 0, stream>>>(scores, ebArr, gmax, cursor, perm, gsum);
  k_accum2 <<<NB * SPLIT, 256, 0, stream>>>((const unsigned*)vprime, scores, gmax, offs, perm, xpart);
  k_final  <<<NB, D, 0, stream>>>(xpart, gsum, Wl, bl, out);
}